// Round 1
// baseline (635.651 us; speedup 1.0000x reference)
//
#include <hip/hip_runtime.h>
#include <hip/hip_bf16.h>

#define NN 20000
#define NE 160000
#define CPB 16   // workgroup slots per bucket

typedef __attribute__((ext_vector_type(8))) short short8;
typedef __attribute__((ext_vector_type(4))) float floatx4;

__device__ __forceinline__ short f2bf(float f) {
    unsigned u = __float_as_uint(f);
    u += 0x7fff + ((u >> 16) & 1);   // RNE
    return (short)(u >> 16);
}

// ---------------- K1: anchor + histogram + degree ----------------
__global__ void k_count(const float* __restrict__ pseudo, const int* __restrict__ ei,
                        int* __restrict__ cnt, int* __restrict__ degi, int* __restrict__ anchor) {
    int e = blockIdx.x * 256 + threadIdx.x;
    if (e >= NE) return;
    float p0 = pseudo[e*3+0], p1 = pseudo[e*3+1], p2 = pseudo[e*3+2];
    int v0 = min(3, max(0, (int)floorf(p0 * 4.f)));
    int v1 = min(3, max(0, (int)floorf(p1 * 4.f)));
    int v2 = min(3, max(0, (int)floorf(p2 * 4.f)));
    int a = v0 + 4*v1 + 16*v2;
    anchor[e] = a;
    atomicAdd(&cnt[a], 1);
    atomicAdd(&degi[ei[e]], 1);
}

// ---------------- K2: exclusive scan over 64 bins ----------------
__global__ void k_scan(const int* __restrict__ cnt, int* __restrict__ off) {
    if (threadIdx.x == 0) {
        int acc = 0;
        for (int i = 0; i < 64; i++) { off[i] = acc; acc += cnt[i]; }
        off[64] = acc;
    }
}

// ---------------- K2b: reciprocal degree ----------------
__global__ void k_rdeg(const int* __restrict__ degi, float* __restrict__ rdeg) {
    int n = blockIdx.x * 256 + threadIdx.x;
    if (n < NN) rdeg[n] = 1.0f / (float)max(degi[n], 1);
}

// ---------------- K3: scatter edge ids into buckets ----------------
__global__ void k_scatter(const int* __restrict__ anchor, const int* __restrict__ off,
                          int* __restrict__ cur, int* __restrict__ eidx) {
    int e = blockIdx.x * 256 + threadIdx.x;
    if (e >= NE) return;
    int a = anchor[e];
    int p = atomicAdd(&cur[a], 1);
    eidx[off[a] + p] = e;
}

// ---------------- K3.5: pre-permute W into MFMA B-fragment order ----------------
// frag index f = ((nt*16 + t)*64 + lane)*8 + j ; k = 32t + (lane>>4)*8 + j ; n = nt*16 + (lane&15)
// Wcat[k=s*64+i][n] = weight[wbase + boff(s)][i][n]
__global__ void k_wfrag(const float* __restrict__ w, unsigned short* __restrict__ wf) {
    int b = blockIdx.x;
    int b0 = b & 3, b1 = (b >> 2) & 3, b2 = (b >> 4) & 3;
    int wbase = b0 + 5*b1 + 25*b2;
    int n = threadIdx.x & 63;
    for (int k = (threadIdx.x >> 6); k < 512; k += 4) {
        int s = k >> 6, i = k & 63;
        int widx = wbase + (s & 1) + 5*((s >> 1) & 1) + 25*((s >> 2) & 1);
        float val = w[widx*4096 + i*64 + n];            // coalesced over n
        int t = k >> 5, j = k & 7, g = (k >> 3) & 3;
        int l = g*16 + (n & 15), nt = n >> 4;
        int f = ((nt*16 + t)*64 + l)*8 + j;
        wf[b*32768 + f] = (unsigned short)f2bf(val);
    }
}

// ---------------- K4: main bucketed spline GEMM ----------------
__global__ __launch_bounds__(256)
void k_main(const float* __restrict__ x, const int* __restrict__ ei,
            const float* __restrict__ pseudo, const unsigned short* __restrict__ wfrag_g,
            const int* __restrict__ off, const int* __restrict__ eidx,
            const float* __restrict__ rdeg, float* __restrict__ acc_g) {
    __shared__ unsigned short wf[32768];   // 64 KB: B fragments for this bucket
    int b = blockIdx.x & 63;
    int slot = blockIdx.x >> 6;

    {   // stage bucket's W fragments (linear 64 KB copy, L2-hot)
        const int4* src = (const int4*)(wfrag_g + b*32768);
        int4* dst = (int4*)wf;
        for (int i = threadIdx.x; i < 4096; i += 256) dst[i] = src[i];
    }
    __syncthreads();

    int base = off[b];
    int cnt  = off[b+1] - base;
    int wv = threadIdx.x >> 6;      // wave id 0..3
    int l  = threadIdx.x & 63;      // lane
    int er = l & 15;                // edge slot within 16-edge tile
    int g  = l >> 4;                // lane group 0..3

    for (int p0 = slot*64 + wv*16; p0 < cnt; p0 += CPB*64) {
        int m = min(16, cnt - p0);
        bool valid = er < m;
        int e = eidx[base + p0 + (valid ? er : 0)];
        int col = ei[NE + e];

        // spline basis for this lane's edge
        float pa = pseudo[e*3+0] * 4.f;
        float pb = pseudo[e*3+1] * 4.f;
        float pc = pseudo[e*3+2] * 4.f;
        float f0 = pa - floorf(pa);
        float f1 = pb - floorf(pb);
        float f2 = pc - floorf(pc);
        float fb[8];
        #pragma unroll
        for (int s = 0; s < 8; s++) {
            float t0 = (s & 1) ? f0 : 1.f - f0;
            float t1 = (s & 2) ? f1 : 1.f - f1;
            float t2 = (s & 4) ? f2 : 1.f - f2;
            fb[s] = valid ? t0 * t1 * t2 : 0.f;
        }

        // gather this lane's x chunks: i in [g*8, g*8+8) and [32+g*8, ...)
        float xA[8], xB[8];
        {
            const float4* xr = (const float4*)(x + col*64 + g*8);
            float4 a0 = xr[0], a1 = xr[1];
            const float4* xr2 = (const float4*)(x + col*64 + 32 + g*8);
            float4 c0 = xr2[0], c1 = xr2[1];
            xA[0]=a0.x; xA[1]=a0.y; xA[2]=a0.z; xA[3]=a0.w;
            xA[4]=a1.x; xA[5]=a1.y; xA[6]=a1.z; xA[7]=a1.w;
            xB[0]=c0.x; xB[1]=c0.y; xB[2]=c0.z; xB[3]=c0.w;
            xB[4]=c1.x; xB[5]=c1.y; xB[6]=c1.z; xB[7]=c1.w;
        }

        floatx4 acc[4];
        #pragma unroll
        for (int nt = 0; nt < 4; nt++) acc[nt] = (floatx4){0.f, 0.f, 0.f, 0.f};

        #pragma unroll
        for (int t = 0; t < 16; t++) {
            const int s = t >> 1;
            const float* xf = (t & 1) ? xB : xA;
            short8 afrag;
            #pragma unroll
            for (int j = 0; j < 8; j++) afrag[j] = f2bf(fb[s] * xf[j]);
            #pragma unroll
            for (int nt = 0; nt < 4; nt++) {
                short8 bfrag = *(const short8*)&wf[((nt*16 + t)*64 + l)*8];
                acc[nt] = __builtin_amdgcn_mfma_f32_16x16x32_bf16(afrag, bfrag, acc[nt], 0, 0, 0);
            }
        }

        // scatter: D row = g*4 + r (edge slot), col = nt*16 + (l&15)
        #pragma unroll
        for (int r = 0; r < 4; r++) {
            int mr = g*4 + r;
            if (mr < m) {
                int em = eidx[base + p0 + mr];
                int rw = ei[em];
                float sc = rdeg[rw];
                #pragma unroll
                for (int nt = 0; nt < 4; nt++)
                    atomicAdd(&acc_g[rw*64 + nt*16 + (l & 15)], acc[nt][r] * sc);
            }
        }
    }
}

// ---------------- K5: out = acc + x@root + bias ----------------
__global__ void k_final(const float* __restrict__ x, const float* __restrict__ root,
                        const float* __restrict__ bias, const float* __restrict__ acc_g,
                        float* __restrict__ out) {
    __shared__ float rs[4096];
    for (int i = threadIdx.x; i < 4096; i += 256) rs[i] = root[i];
    __syncthreads();
    int n = blockIdx.x * 4 + (threadIdx.x >> 6);
    int o = threadIdx.x & 63;
    const float* xr = x + n*64;
    float v = acc_g[n*64 + o] + bias[o];
    #pragma unroll 8
    for (int i = 0; i < 64; i++) v += xr[i] * rs[i*64 + o];
    out[n*64 + o] = v;
}

extern "C" void kernel_launch(void* const* d_in, const int* in_sizes, int n_in,
                              void* d_out, int out_size, void* d_ws, size_t ws_size,
                              hipStream_t stream) {
    const float* x      = (const float*)d_in[0];
    const int*   ei     = (const int*)d_in[1];      // [2*E] int32 (row | col)
    const float* pseudo = (const float*)d_in[2];
    const float* weight = (const float*)d_in[3];
    const float* root   = (const float*)d_in[4];
    const float* bias   = (const float*)d_in[5];
    float* out = (float*)d_out;
    char* ws = (char*)d_ws;

    float*          acc    = (float*)(ws + 0);              // 5,120,000 B
    int*            degi   = (int*)  (ws + 5120000);        //    80,000 B
    float*          rdeg   = (float*)(ws + 5200000);        //    80,000 B
    int*            cnt    = (int*)  (ws + 5280000);        //       256 B
    int*            off    = (int*)  (ws + 5280256);        //       260 B (pad)
    int*            cur    = (int*)  (ws + 5280768);        //       256 B
    int*            anchor = (int*)  (ws + 5281024);        //   640,000 B
    int*            eidx   = (int*)  (ws + 5921024);        //   640,000 B
    unsigned short* wfg    = (unsigned short*)(ws + 6561024); // 4,194,304 B  (total ~10.76 MB)

    // zero acc, degi, cnt, off, cur (rdeg fully overwritten)
    hipMemsetAsync(ws, 0, 5281024, stream);

    k_count  <<<(NE + 255)/256, 256, 0, stream>>>(pseudo, ei, cnt, degi, anchor);
    k_scan   <<<1, 64, 0, stream>>>(cnt, off);
    k_rdeg   <<<(NN + 255)/256, 256, 0, stream>>>(degi, rdeg);
    k_scatter<<<(NE + 255)/256, 256, 0, stream>>>(anchor, off, cur, eidx);
    k_wfrag  <<<64, 256, 0, stream>>>(weight, wfg);
    k_main   <<<64*CPB, 256, 0, stream>>>(x, ei, pseudo, wfg, off, eidx, rdeg, acc);
    k_final  <<<NN/4, 256, 0, stream>>>(x, root, bias, acc, out);
}

// Round 2
// 166.254 us; speedup vs baseline: 3.8234x; 3.8234x over previous
//
#include <hip/hip_runtime.h>
#include <hip/hip_bf16.h>

#define NN 20000
#define NE 160000
#define CPB 16   // workgroup slots per bucket

typedef __attribute__((ext_vector_type(8))) short short8;
typedef __attribute__((ext_vector_type(4))) float floatx4;

__device__ __forceinline__ short f2bf(float f) {
    unsigned u = __float_as_uint(f);
    u += 0x7fff + ((u >> 16) & 1);   // RNE
    return (short)(u >> 16);
}

// ---------------- K1: anchor + LDS histogram + degree ----------------
// cntp is padded: bin i lives at cntp[i*32] (one 128B line per bin).
__global__ void k_count(const float* __restrict__ pseudo, const int* __restrict__ ei,
                        int* __restrict__ cntp, int* __restrict__ degi, int* __restrict__ anchor) {
    __shared__ int lh[64];
    int tid = threadIdx.x;
    if (tid < 64) lh[tid] = 0;
    __syncthreads();
    int e = blockIdx.x * 256 + tid;
    if (e < NE) {
        float p0 = pseudo[e*3+0], p1 = pseudo[e*3+1], p2 = pseudo[e*3+2];
        int v0 = min(3, max(0, (int)floorf(p0 * 4.f)));
        int v1 = min(3, max(0, (int)floorf(p1 * 4.f)));
        int v2 = min(3, max(0, (int)floorf(p2 * 4.f)));
        int a = v0 + 4*v1 + 16*v2;
        anchor[e] = a;
        atomicAdd(&lh[a], 1);                 // LDS atomic (block-local)
        atomicAdd(&degi[ei[e]], 1);           // spread over 20000 addrs — fine
    }
    __syncthreads();
    if (tid < 64 && lh[tid]) atomicAdd(&cntp[tid*32], lh[tid]);  // 625/line
}

// ---------------- K2: exclusive scan over 64 bins ----------------
__global__ void k_scan(const int* __restrict__ cntp, int* __restrict__ off) {
    if (threadIdx.x == 0) {
        int acc = 0;
        for (int i = 0; i < 64; i++) { off[i] = acc; acc += cntp[i*32]; }
        off[64] = acc;
    }
}

// ---------------- K2b: reciprocal degree ----------------
__global__ void k_rdeg(const int* __restrict__ degi, float* __restrict__ rdeg) {
    int n = blockIdx.x * 256 + threadIdx.x;
    if (n < NN) rdeg[n] = 1.0f / (float)max(degi[n], 1);
}

// ---------------- K3: scatter edge ids into buckets ----------------
// LDS rank + one padded global atomic per (block,bin).
__global__ void k_scatter(const int* __restrict__ anchor, const int* __restrict__ off,
                          int* __restrict__ curp, int* __restrict__ eidx) {
    __shared__ int lh[64];
    __shared__ int gb[64];
    int tid = threadIdx.x;
    if (tid < 64) lh[tid] = 0;
    __syncthreads();
    int e = blockIdx.x * 256 + tid;
    int a = 0, r = 0;
    if (e < NE) {
        a = anchor[e];
        r = atomicAdd(&lh[a], 1);             // rank within block
    }
    __syncthreads();
    if (tid < 64) gb[tid] = lh[tid] ? atomicAdd(&curp[tid*32], lh[tid]) : 0;
    __syncthreads();
    if (e < NE) eidx[off[a] + gb[a] + r] = e;
}

// ---------------- K3.5: pre-permute W into MFMA B-fragment order ----------------
// frag index f = ((nt*16 + t)*64 + lane)*8 + j ; k = 32t + (lane>>4)*8 + j ; n = nt*16 + (lane&15)
// Wcat[k=s*64+i][n] = weight[wbase + boff(s)][i][n]
__global__ void k_wfrag(const float* __restrict__ w, unsigned short* __restrict__ wf) {
    int b = blockIdx.x;
    int b0 = b & 3, b1 = (b >> 2) & 3, b2 = (b >> 4) & 3;
    int wbase = b0 + 5*b1 + 25*b2;
    int n = threadIdx.x & 63;
    for (int k = (threadIdx.x >> 6); k < 512; k += 4) {
        int s = k >> 6, i = k & 63;
        int widx = wbase + (s & 1) + 5*((s >> 1) & 1) + 25*((s >> 2) & 1);
        float val = w[widx*4096 + i*64 + n];            // coalesced over n
        int t = k >> 5, j = k & 7, g = (k >> 3) & 3;
        int l = g*16 + (n & 15), nt = n >> 4;
        int f = ((nt*16 + t)*64 + l)*8 + j;
        wf[b*32768 + f] = (unsigned short)f2bf(val);
    }
}

// ---------------- K4: main bucketed spline GEMM ----------------
__global__ __launch_bounds__(256)
void k_main(const float* __restrict__ x, const int* __restrict__ ei,
            const float* __restrict__ pseudo, const unsigned short* __restrict__ wfrag_g,
            const int* __restrict__ off, const int* __restrict__ eidx,
            const float* __restrict__ rdeg, float* __restrict__ acc_g) {
    __shared__ unsigned short wf[32768];   // 64 KB: B fragments for this bucket
    int b = blockIdx.x & 63;
    int slot = blockIdx.x >> 6;

    {   // stage bucket's W fragments (linear 64 KB copy, L2-hot)
        const int4* src = (const int4*)(wfrag_g + b*32768);
        int4* dst = (int4*)wf;
        for (int i = threadIdx.x; i < 4096; i += 256) dst[i] = src[i];
    }
    __syncthreads();

    int base = off[b];
    int cnt  = off[b+1] - base;
    int wv = threadIdx.x >> 6;      // wave id 0..3
    int l  = threadIdx.x & 63;      // lane
    int er = l & 15;                // edge slot within 16-edge tile
    int g  = l >> 4;                // lane group 0..3

    for (int p0 = slot*64 + wv*16; p0 < cnt; p0 += CPB*64) {
        int m = min(16, cnt - p0);
        bool valid = er < m;
        int e = eidx[base + p0 + (valid ? er : 0)];
        int col = ei[NE + e];

        // spline basis for this lane's edge
        float pa = pseudo[e*3+0] * 4.f;
        float pb = pseudo[e*3+1] * 4.f;
        float pc = pseudo[e*3+2] * 4.f;
        float f0 = pa - floorf(pa);
        float f1 = pb - floorf(pb);
        float f2 = pc - floorf(pc);
        float fb[8];
        #pragma unroll
        for (int s = 0; s < 8; s++) {
            float t0 = (s & 1) ? f0 : 1.f - f0;
            float t1 = (s & 2) ? f1 : 1.f - f1;
            float t2 = (s & 4) ? f2 : 1.f - f2;
            fb[s] = valid ? t0 * t1 * t2 : 0.f;
        }

        // gather this lane's x chunks: i in [g*8, g*8+8) and [32+g*8, ...)
        float xA[8], xB[8];
        {
            const float4* xr = (const float4*)(x + col*64 + g*8);
            float4 a0 = xr[0], a1 = xr[1];
            const float4* xr2 = (const float4*)(x + col*64 + 32 + g*8);
            float4 c0 = xr2[0], c1 = xr2[1];
            xA[0]=a0.x; xA[1]=a0.y; xA[2]=a0.z; xA[3]=a0.w;
            xA[4]=a1.x; xA[5]=a1.y; xA[6]=a1.z; xA[7]=a1.w;
            xB[0]=c0.x; xB[1]=c0.y; xB[2]=c0.z; xB[3]=c0.w;
            xB[4]=c1.x; xB[5]=c1.y; xB[6]=c1.z; xB[7]=c1.w;
        }

        floatx4 acc[4];
        #pragma unroll
        for (int nt = 0; nt < 4; nt++) acc[nt] = (floatx4){0.f, 0.f, 0.f, 0.f};

        #pragma unroll
        for (int t = 0; t < 16; t++) {
            const int s = t >> 1;
            const float* xf = (t & 1) ? xB : xA;
            short8 afrag;
            #pragma unroll
            for (int j = 0; j < 8; j++) afrag[j] = f2bf(fb[s] * xf[j]);
            #pragma unroll
            for (int nt = 0; nt < 4; nt++) {
                short8 bfrag = *(const short8*)&wf[((nt*16 + t)*64 + l)*8];
                acc[nt] = __builtin_amdgcn_mfma_f32_16x16x32_bf16(afrag, bfrag, acc[nt], 0, 0, 0);
            }
        }

        // scatter: D row = g*4 + r (edge slot), col = nt*16 + (l&15)
        #pragma unroll
        for (int r = 0; r < 4; r++) {
            int mr = g*4 + r;
            if (mr < m) {
                int em = eidx[base + p0 + mr];
                int rw = ei[em];
                float sc = rdeg[rw];
                #pragma unroll
                for (int nt = 0; nt < 4; nt++)
                    atomicAdd(&acc_g[rw*64 + nt*16 + (l & 15)], acc[nt][r] * sc);
            }
        }
    }
}

// ---------------- K5: out = acc + x@root + bias ----------------
__global__ void k_final(const float* __restrict__ x, const float* __restrict__ root,
                        const float* __restrict__ bias, const float* __restrict__ acc_g,
                        float* __restrict__ out) {
    __shared__ float rs[4096];
    for (int i = threadIdx.x; i < 4096; i += 256) rs[i] = root[i];
    __syncthreads();
    int n = blockIdx.x * 4 + (threadIdx.x >> 6);
    int o = threadIdx.x & 63;
    const float* xr = x + n*64;
    float v = acc_g[n*64 + o] + bias[o];
    #pragma unroll 8
    for (int i = 0; i < 64; i++) v += xr[i] * rs[i*64 + o];
    out[n*64 + o] = v;
}

extern "C" void kernel_launch(void* const* d_in, const int* in_sizes, int n_in,
                              void* d_out, int out_size, void* d_ws, size_t ws_size,
                              hipStream_t stream) {
    const float* x      = (const float*)d_in[0];
    const int*   ei     = (const int*)d_in[1];      // [2*E] int32 (row | col)
    const float* pseudo = (const float*)d_in[2];
    const float* weight = (const float*)d_in[3];
    const float* root   = (const float*)d_in[4];
    const float* bias   = (const float*)d_in[5];
    float* out = (float*)d_out;
    char* ws = (char*)d_ws;

    float*          acc    = (float*)(ws + 0);                //  5,120,000 B
    int*            degi   = (int*)  (ws + 5120000);          //     80,000 B
    int*            cntp   = (int*)  (ws + 5200000);          //      8,192 B (padded: bin i at [i*32])
    int*            curp   = (int*)  (ws + 5208192);          //      8,192 B (padded)
    int*            off    = (int*)  (ws + 5216384);          //        384 B (65 ints, padded)
    float*          rdeg   = (float*)(ws + 5216768);          //     80,000 B
    int*            anchor = (int*)  (ws + 5296768);          //    640,000 B
    int*            eidx   = (int*)  (ws + 5936768);          //    640,000 B
    unsigned short* wfg    = (unsigned short*)(ws + 6576768); //  4,194,304 B  (total ~10.77 MB)

    // zero acc, degi, cntp, curp, off (rdeg/anchor/eidx fully overwritten)
    hipMemsetAsync(ws, 0, 5216768, stream);

    k_count  <<<(NE + 255)/256, 256, 0, stream>>>(pseudo, ei, cntp, degi, anchor);
    k_scan   <<<1, 64, 0, stream>>>(cntp, off);
    k_rdeg   <<<(NN + 255)/256, 256, 0, stream>>>(degi, rdeg);
    k_scatter<<<(NE + 255)/256, 256, 0, stream>>>(anchor, off, curp, eidx);
    k_wfrag  <<<64, 256, 0, stream>>>(weight, wfg);
    k_main   <<<64*CPB, 256, 0, stream>>>(x, ei, pseudo, wfg, off, eidx, rdeg, acc);
    k_final  <<<NN/4, 256, 0, stream>>>(x, root, bias, acc, out);
}